// Round 6
// baseline (645.967 us; speedup 1.0000x reference)
//
#include <hip/hip_runtime.h>
#include <hip/hip_fp16.h>

#define D 128

typedef _Float16 half8 __attribute__((ext_vector_type(8)));
typedef float floatx16 __attribute__((ext_vector_type(16)));

__device__ inline float2 h2f(unsigned int u) {
  __half2 h = *(__half2*)&u;
  return __half22float2(h);
}

// Slab layout for feature matrices: 8 slabs of 16 columns; slab s, node n occupies
// halves [s*N*16 + n*16, +16) == uint4 indices [s*N*2 + n*2, +2). Column c of node n:
// slab c>>4, offset n*16 + (c&15).

// ---------------- CSR build ----------------
__global__ void hist_kernel(const int* __restrict__ dst, int* __restrict__ cnt, int E) {
  int e = blockIdx.x * blockDim.x + threadIdx.x;
  if (e < E) atomicAdd(&cnt[__builtin_nontemporal_load(dst + e)], 1);
}

#define SCAN_TPB 256
#define SCAN_EPT 8
#define SCAN_CHUNK (SCAN_TPB * SCAN_EPT)  // 2048

__global__ void scan1_kernel(const int* __restrict__ cnt, int* __restrict__ rowptr,
                             int* __restrict__ bsums, int N) {
  __shared__ int lds[SCAN_TPB];
  int tid = threadIdx.x;
  int base = blockIdx.x * SCAN_CHUNK + tid * SCAN_EPT;
  int v[SCAN_EPT];
  int tsum = 0;
#pragma unroll
  for (int j = 0; j < SCAN_EPT; j++) {
    int i = base + j;
    v[j] = (i < N) ? cnt[i] : 0;
    tsum += v[j];
  }
  lds[tid] = tsum;
  __syncthreads();
  for (int off = 1; off < SCAN_TPB; off <<= 1) {
    int t = (tid >= off) ? lds[tid - off] : 0;
    __syncthreads();
    lds[tid] += t;
    __syncthreads();
  }
  int excl = lds[tid] - tsum;
  if (tid == SCAN_TPB - 1) bsums[blockIdx.x] = lds[tid];
  int run = excl;
#pragma unroll
  for (int j = 0; j < SCAN_EPT; j++) {
    int i = base + j;
    if (i < N) rowptr[i] = run;
    run += v[j];
  }
}

__global__ void scan2_kernel(int* bsums, int nb) {
  if (threadIdx.x == 0 && blockIdx.x == 0) {
    int run = 0;
    for (int i = 0; i < nb; i++) { int t = bsums[i]; bsums[i] = run; run += t; }
  }
}

__global__ void scan3_kernel(int* __restrict__ rowptr, const int* __restrict__ bsums,
                             int N, int E) {
  int tid = threadIdx.x;
  int base = blockIdx.x * SCAN_CHUNK + tid * SCAN_EPT;
  int off = bsums[blockIdx.x];
#pragma unroll
  for (int j = 0; j < SCAN_EPT; j++) {
    int i = base + j;
    if (i < N) rowptr[i] += off;
  }
  if (blockIdx.x == 0 && tid == 0) rowptr[N] = E;
}

// XCD-partitioned scatter; streaming reads are NON-TEMPORAL so they don't evict
// the L2-resident csr slice (dirty lines now fill completely before writeback).
#define SC_EPT 8
__global__ void scatter_kernel(const int* __restrict__ src, const int* __restrict__ dst,
                               const int* __restrict__ rowptr, int* __restrict__ cursor,
                               int* __restrict__ csr_src, int E, int N) {
  int seg = blockIdx.x & 7;
  int chunk = blockIdx.x >> 3;
  int lo = (int)((long long)seg * N / 8);
  int hi = (int)((long long)(seg + 1) * N / 8);
  int base = chunk * (256 * SC_EPT) + threadIdx.x;
#pragma unroll
  for (int j = 0; j < SC_EPT; j++) {
    int e = base + j * 256;
    if (e < E) {
      int d = __builtin_nontemporal_load(dst + e);
      if (d >= lo && d < hi) {
        int pos = rowptr[d] + atomicAdd(&cursor[d], 1);
        csr_src[pos] = __builtin_nontemporal_load(src + e);
      }
    }
  }
}

// ---------------- hx = fp16(emb[x]) into SLAB layout ----------------
__global__ void cast_kernel(const float* __restrict__ emb, const int* __restrict__ x,
                            __half* __restrict__ hx, int N) {
  int w = (int)((blockIdx.x * (unsigned)blockDim.x + threadIdx.x) >> 6);
  int lane = threadIdx.x & 63;
  if (w >= N) return;
  int xi = x[w];
  float2 v = ((const float2*)(emb + (size_t)xi * D))[lane];  // cols 2*lane, 2*lane+1
  int s = lane >> 3;
  int j = lane & 7;
  ((__half2*)(hx + (size_t)s * N * 16))[(size_t)w * 8 + j] = __floats2half2_rn(v.x, v.y);
}

// ---------------- mean aggregation: slab-sliced, 2 lanes/node, L2-resident slab ----
// block b: column-slab s = b&7 (3.2 MB -> L2-resident per XCD), nodes chunk = b>>3.
__global__ void agg_kernel(const __half* __restrict__ hslab, const int* __restrict__ rowptr,
                           const int* __restrict__ csr, __half* __restrict__ mslab, int N) {
  int s = blockIdx.x & 7;
  int chunk = blockIdx.x >> 3;
  int t = threadIdx.x;
  int node = chunk * 128 + (t >> 1);
  int part = t & 1;  // which uint4 (16B) of the 32B slice
  if (node >= N) return;
  const uint4* tbl = (const uint4*)(hslab + (size_t)s * N * 16);
  int beg = __builtin_nontemporal_load(rowptr + node);
  int end = __builtin_nontemporal_load(rowptr + node + 1);
  float2 a0 = {0.f, 0.f}, a1 = {0.f, 0.f}, a2 = {0.f, 0.f}, a3 = {0.f, 0.f};
  int e = beg;
  for (; e + 8 <= end; e += 8) {
    int si[8];
#pragma unroll
    for (int j = 0; j < 8; j++) si[j] = __builtin_nontemporal_load(csr + e + j);
    uint4 r[8];
#pragma unroll
    for (int j = 0; j < 8; j++) r[j] = tbl[(size_t)si[j] * 2 + part];
#pragma unroll
    for (int j = 0; j < 8; j++) {
      float2 f0 = h2f(r[j].x), f1 = h2f(r[j].y), f2 = h2f(r[j].z), f3 = h2f(r[j].w);
      a0.x += f0.x; a0.y += f0.y; a1.x += f1.x; a1.y += f1.y;
      a2.x += f2.x; a2.y += f2.y; a3.x += f3.x; a3.y += f3.y;
    }
  }
  for (; e < end; e++) {
    int si = __builtin_nontemporal_load(csr + e);
    uint4 r = tbl[(size_t)si * 2 + part];
    float2 f0 = h2f(r.x), f1 = h2f(r.y), f2 = h2f(r.z), f3 = h2f(r.w);
    a0.x += f0.x; a0.y += f0.y; a1.x += f1.x; a1.y += f1.y;
    a2.x += f2.x; a2.y += f2.y; a3.x += f3.x; a3.y += f3.y;
  }
  float inv = 1.0f / fmaxf((float)(end - beg), 1.0f);
  __half2 o[4];
  o[0] = __floats2half2_rn(a0.x * inv, a0.y * inv);
  o[1] = __floats2half2_rn(a1.x * inv, a1.y * inv);
  o[2] = __floats2half2_rn(a2.x * inv, a2.y * inv);
  o[3] = __floats2half2_rn(a3.x * inv, a3.y * inv);
  ((uint4*)(mslab + (size_t)s * N * 16))[(size_t)node * 2 + part] = *(uint4*)o;
}

// ---------------- pack W into B-fragment order ----------------
__global__ void packW_kernel(const float* __restrict__ Wl, const float* __restrict__ Wr,
                             uint4* __restrict__ gWsw) {
  int g = blockIdx.x * blockDim.x + threadIdx.x;
  if (g >= 4096) return;
  int lane = g & 63;
  int k0 = (g >> 6) & 15;
  int t = g >> 10;
  int n = t * 32 + (lane & 31);
  int kk = k0 * 16 + (lane >> 5) * 8;
  const float* srcp = (kk < D) ? (Wl + (size_t)n * D + kk) : (Wr + (size_t)n * D + (kk - D));
  float4 f0 = *(const float4*)(srcp);
  float4 f1 = *(const float4*)(srcp + 4);
  __half h[8];
  h[0] = __float2half_rn(f0.x); h[1] = __float2half_rn(f0.y);
  h[2] = __float2half_rn(f0.z); h[3] = __float2half_rn(f0.w);
  h[4] = __float2half_rn(f1.x); h[5] = __float2half_rn(f1.y);
  h[6] = __float2half_rn(f1.z); h[7] = __float2half_rn(f1.w);
  gWsw[g] = *(uint4*)h;
}

// ---------------- MFMA GEMM: out = fp16(relu([mean|h] @ B + bias)) ----------------
// A inputs in slab layout. out_slab=1 -> slab layout, 0 -> row layout.
#define OS_PITCH 136

__global__ __launch_bounds__(256) void mfma_gemm_kernel(
    const __half* __restrict__ mslab, const __half* __restrict__ hslab,
    const uint4* __restrict__ gWsw, const float* __restrict__ bias,
    __half* __restrict__ out, int N, int out_slab) {
  __shared__ uint4 lds[4096];  // 64 KB
  int tid = threadIdx.x;
  int wave = tid >> 6, lane = tid & 63;
  int row0 = blockIdx.x * 128;

#pragma unroll
  for (int i = 0; i < 16; i++) lds[i * 256 + tid] = gWsw[i * 256 + tid];
  __syncthreads();

  int mrow = row0 + wave * 32 + (lane & 31);
  int koff = (lane >> 5) * 8;
  bool valid = mrow < N;
  size_t abase = (size_t)mrow * 16 + koff;
  size_t sstride = (size_t)N * 16;

  floatx16 acc[4];
#pragma unroll
  for (int t = 0; t < 4; t++)
#pragma unroll
    for (int i = 0; i < 16; i++) acc[t][i] = 0.f;

  uint4 areg[8];
#pragma unroll
  for (int k0 = 0; k0 < 8; k0++) {
    areg[k0] = valid ? *(const uint4*)(mslab + k0 * sstride + abase) : make_uint4(0u, 0u, 0u, 0u);
  }
#pragma unroll
  for (int k0 = 0; k0 < 8; k0++) {
    half8 af = *(half8*)&areg[k0];
#pragma unroll
    for (int t = 0; t < 4; t++) {
      half8 bf = *(half8*)&lds[(t * 16 + k0) * 64 + lane];
      acc[t] = __builtin_amdgcn_mfma_f32_32x32x16_f16(af, bf, acc[t], 0, 0, 0);
    }
  }
#pragma unroll
  for (int k0 = 0; k0 < 8; k0++) {
    areg[k0] = valid ? *(const uint4*)(hslab + k0 * sstride + abase) : make_uint4(0u, 0u, 0u, 0u);
  }
#pragma unroll
  for (int k0 = 8; k0 < 16; k0++) {
    half8 af = *(half8*)&areg[k0 - 8];
#pragma unroll
    for (int t = 0; t < 4; t++) {
      half8 bf = *(half8*)&lds[(t * 16 + k0) * 64 + lane];
      acc[t] = __builtin_amdgcn_mfma_f32_32x32x16_f16(af, bf, acc[t], 0, 0, 0);
    }
  }

  __syncthreads();
  __half* Os = (__half*)lds;
  int col = lane & 31;
  int rsub = 4 * (lane >> 5);
#pragma unroll
  for (int t = 0; t < 4; t++) {
    float bv = bias[t * 32 + col];
#pragma unroll
    for (int r = 0; r < 16; r++) {
      int row = (r & 3) + 8 * (r >> 2) + rsub;
      float v = fmaxf(acc[t][r] + bv, 0.f);
      Os[(size_t)(wave * 32 + row) * OS_PITCH + t * 32 + col] = __float2half_rn(v);
    }
  }
  __syncthreads();
#pragma unroll
  for (int i = 0; i < 8; i++) {
    int idx = i * 256 + tid;
    int row = idx >> 4;
    int c16 = idx & 15;  // uint4 index within row (8 halves)
    int grow = row0 + row;
    if (grow < N) {
      uint4 v = *(uint4*)(Os + (size_t)row * OS_PITCH + c16 * 8);
      if (out_slab) {
        *(uint4*)(out + (size_t)(c16 >> 1) * sstride + (size_t)grow * 16 + (c16 & 1) * 8) = v;
      } else {
        *(uint4*)(out + (size_t)grow * D + c16 * 8) = v;
      }
    }
  }
}

// ---------------- pair dot: 16 lanes/pair, 4 pairs/quarter (row-layout h) ----------
__global__ void pairdot_kernel(const __half* __restrict__ h, const int2* __restrict__ pairs,
                               float* __restrict__ out, int P) {
  int wid = (int)((blockIdx.x * (unsigned)blockDim.x + threadIdx.x) >> 6);
  int lane = threadIdx.x & 63;
  int q = lane >> 4;
  int sub = lane & 15;
  int base = wid * 16;

  int p[4];
  int2 pr[4];
#pragma unroll
  for (int j = 0; j < 4; j++) {
    p[j] = base + j * 4 + q;
    pr[j] = (p[j] < P) ? pairs[p[j]] : make_int2(0, 0);
  }
  uint4 ur[4], vr[4];
#pragma unroll
  for (int j = 0; j < 4; j++) {
    ur[j] = *(const uint4*)(h + (size_t)pr[j].x * D + sub * 8);
    vr[j] = *(const uint4*)(h + (size_t)pr[j].y * D + sub * 8);
  }
#pragma unroll
  for (int j = 0; j < 4; j++) {
    float2 a0 = h2f(ur[j].x), a1 = h2f(ur[j].y), a2 = h2f(ur[j].z), a3 = h2f(ur[j].w);
    float2 b0 = h2f(vr[j].x), b1 = h2f(vr[j].y), b2 = h2f(vr[j].z), b3 = h2f(vr[j].w);
    float s = a0.x * b0.x + a0.y * b0.y + a1.x * b1.x + a1.y * b1.y +
              a2.x * b2.x + a2.y * b2.y + a3.x * b3.x + a3.y * b3.y;
#pragma unroll
    for (int off = 1; off <= 8; off <<= 1) s += __shfl_xor(s, off);
    if (sub == 0 && p[j] < P) out[p[j]] = s;
  }
}

// ---------------- launcher ----------------
extern "C" void kernel_launch(void* const* d_in, const int* in_sizes, int n_in,
                              void* d_out, int out_size, void* d_ws, size_t ws_size,
                              hipStream_t stream) {
  const int*   x     = (const int*)d_in[0];
  const int*   eidx  = (const int*)d_in[1];
  const int*   pairs = (const int*)d_in[2];
  const float* emb   = (const float*)d_in[3];
  const float* Wl0   = (const float*)d_in[4];
  const float* bl0   = (const float*)d_in[5];
  const float* Wr0   = (const float*)d_in[6];
  const float* Wl1   = (const float*)d_in[7];
  const float* bl1   = (const float*)d_in[8];
  const float* Wr1   = (const float*)d_in[9];

  const int N = in_sizes[0];
  const int E = in_sizes[1] / 2;
  const int P = in_sizes[2] / 2;
  const int* src = eidx;
  const int* dst = eidx + E;

  char* ws = (char*)d_ws;
  size_t off = 0;
  __half* hx   = (__half*)(ws + off); off += (size_t)N * D * sizeof(__half);  // slab: hx -> h1
  __half* mh   = (__half*)(ws + off); off += (size_t)N * D * sizeof(__half);  // slab: mean
  __half* hrow = (__half*)(ws + off); off += (size_t)N * D * sizeof(__half);  // row: h2
  int* rowptr = (int*)(ws + off);    off += ((size_t)N + 64) * sizeof(int);
  int* cnt    = (int*)(ws + off);    off += ((size_t)N + 64) * sizeof(int);
  int* cursor = (int*)(ws + off);    off += ((size_t)N + 64) * sizeof(int);
  int* bsums  = (int*)(ws + off);    off += 4096;
  uint4* gW0  = (uint4*)(ws + off);  off += 65536;
  uint4* gW1  = (uint4*)(ws + off);  off += 65536;
  int* csr    = (int*)(ws + off);    off += (size_t)E * sizeof(int);
  (void)ws_size; (void)n_in; (void)out_size;

  hipMemsetAsync(cnt, 0, (size_t)N * sizeof(int), stream);
  hipMemsetAsync(cursor, 0, (size_t)N * sizeof(int), stream);

  int nbE = (E + 255) / 256;
  int nbS = (N + SCAN_CHUNK - 1) / SCAN_CHUNK;
  hist_kernel<<<nbE, 256, 0, stream>>>(dst, cnt, E);
  scan1_kernel<<<nbS, SCAN_TPB, 0, stream>>>(cnt, rowptr, bsums, N);
  scan2_kernel<<<1, 64, 0, stream>>>(bsums, nbS);
  scan3_kernel<<<nbS, SCAN_TPB, 0, stream>>>(rowptr, bsums, N, E);

  int nchunk = (E + 256 * SC_EPT - 1) / (256 * SC_EPT);
  scatter_kernel<<<nchunk * 8, 256, 0, stream>>>(src, dst, rowptr, cursor, csr, E, N);

  packW_kernel<<<16, 256, 0, stream>>>(Wl0, Wr0, gW0);
  packW_kernel<<<16, 256, 0, stream>>>(Wl1, Wr1, gW1);

  int nbC = (N + 3) / 4;
  int nbA = 8 * ((N + 127) / 128);
  int nbG = (N + 127) / 128;

  cast_kernel<<<nbC, 256, 0, stream>>>(emb, x, hx, N);

  agg_kernel<<<nbA, 256, 0, stream>>>(hx, rowptr, csr, mh, N);
  mfma_gemm_kernel<<<nbG, 256, 0, stream>>>(mh, hx, gW0, bl0, hx, N, 1);   // hx := h1 (slab)
  agg_kernel<<<nbA, 256, 0, stream>>>(hx, rowptr, csr, mh, N);
  mfma_gemm_kernel<<<nbG, 256, 0, stream>>>(mh, hx, gW1, bl1, hrow, N, 0); // hrow := h2 (row)

  int nbP = (P + 63) / 64;
  pairdot_kernel<<<nbP, 256, 0, stream>>>(hrow, (const int2*)pairs, (float*)d_out, P);
}